// Round 16
// baseline (63.998 us; speedup 1.0000x reference)
//
#include <hip/hip_runtime.h>

typedef float f32x4 __attribute__((ext_vector_type(4)));
typedef _Float16 f16;
typedef f16 f16x4 __attribute__((ext_vector_type(4)));
typedef f16 f16x8 __attribute__((ext_vector_type(8)));

// out[e] = relu(relu(features[src[e]] @ W1 + b1) @ W2 + b2)
// R16: split formulation with LEAN gather.
//   k1: per-node MFMA MLP (reads f32 features sequentially), Y stored f16 in ws.
//   k2: minimal gather: 8B f16 read (6.4MB L2/L3-resident table) -> cvt ->
//       16B NT f32 store. ~10 VGPR -> full occupancy, no compute interleave.
// Tests whether the fused kernel's 48us was memory-profile-bound or
// structure-bound (store issue starved by low-TLP compute chains).

// ---------------- per-node MFMA MLP -> Y f16 ----------------
// Layouts verified R6-R15. One wave = one 16-node x 64-col tile.
__global__ __launch_bounds__(256) void mlp_f16_kernel(
    const float* __restrict__ feat,  // [N][64] f32
    const float* __restrict__ W1, const float* __restrict__ b1,
    const float* __restrict__ W2, const float* __restrict__ b2,
    f16* __restrict__ Y, int N, int ntiles)
{
    __shared__ f16 hl[4][16][72];   // h transpose staging, per wave
    __shared__ f16 ol[4][16][72];   // Y-tile staging (f16), per wave

    const int lane = threadIdx.x & 63;
    const int wv   = threadIdx.x >> 6;
    const int l15  = lane & 15;
    const int q    = lane >> 4;

    const int gw = blockIdx.x * 4 + wv;
    const int nw = gridDim.x * 4;

    // Weight fragments in registers for the whole kernel (64 VGPRs).
    f16x8 B1f[4][2], B2f[4][2];
    #pragma unroll
    for (int t = 0; t < 4; ++t) {
        #pragma unroll
        for (int s = 0; s < 2; ++s) {
            f16x8 r1, r2;
            #pragma unroll
            for (int j = 0; j < 8; ++j) {
                const int kk = s * 32 + q * 8 + j;
                r1[j] = (f16)W1[kk * 64 + t * 16 + l15];
                r2[j] = (f16)W2[kk * 64 + t * 16 + l15];
            }
            B1f[t][s] = r1;
            B2f[t][s] = r2;
        }
    }
    float bb1[4], bb2[4];
    #pragma unroll
    for (int t = 0; t < 4; ++t) {
        bb1[t] = b1[t * 16 + l15];
        bb2[t] = b2[t * 16 + l15];
    }

    const int srow = lane >> 2;          // Y-store mapping: lane -> row
    const int scol = (lane & 3) * 16;    //                  lane -> col base

    for (int tile = gw; tile < ntiles; tile += nw) {
        const int r0 = tile << 4;
        const int rr = (r0 + l15 < N) ? (r0 + l15) : (N - 1);
        const float* p = feat + (long long)rr * 64;

        // A fragments: sequential f32 row reads, cvt to f16.
        f16x8 A0, A1;
        {
            const f32x4 u0 = *(const f32x4*)(p + q * 8);
            const f32x4 u1 = *(const f32x4*)(p + q * 8 + 4);
            const f32x4 u2 = *(const f32x4*)(p + 32 + q * 8);
            const f32x4 u3 = *(const f32x4*)(p + 32 + q * 8 + 4);
            #pragma unroll
            for (int j = 0; j < 4; ++j) {
                A0[j] = (f16)u0[j]; A0[4 + j] = (f16)u1[j];
                A1[j] = (f16)u2[j]; A1[4 + j] = (f16)u3[j];
            }
        }

        // Layer 1: h = relu(x @ W1 + b1).
        f32x4 acc[4];
        #pragma unroll
        for (int t = 0; t < 4; ++t) acc[t] = (f32x4){bb1[t], bb1[t], bb1[t], bb1[t]};
        #pragma unroll
        for (int t = 0; t < 4; ++t) {
            acc[t] = __builtin_amdgcn_mfma_f32_16x16x32_f16(A0, B1f[t][0], acc[t], 0, 0, 0);
            acc[t] = __builtin_amdgcn_mfma_f32_16x16x32_f16(A1, B1f[t][1], acc[t], 0, 0, 0);
        }
        #pragma unroll
        for (int t = 0; t < 4; ++t)
            #pragma unroll
            for (int i = 0; i < 4; ++i)
                hl[wv][q * 4 + i][t * 16 + l15] = (f16)fmaxf(acc[t][i], 0.0f);

        const f16x8 A2a = *(const f16x8*)&hl[wv][l15][q * 8];
        const f16x8 A2b = *(const f16x8*)&hl[wv][l15][32 + q * 8];

        // Layer 2: y = relu(h @ W2 + b2).
        f32x4 acc2[4];
        #pragma unroll
        for (int t = 0; t < 4; ++t) acc2[t] = (f32x4){bb2[t], bb2[t], bb2[t], bb2[t]};
        #pragma unroll
        for (int t = 0; t < 4; ++t) {
            acc2[t] = __builtin_amdgcn_mfma_f32_16x16x32_f16(A2a, B2f[t][0], acc2[t], 0, 0, 0);
            acc2[t] = __builtin_amdgcn_mfma_f32_16x16x32_f16(A2b, B2f[t][1], acc2[t], 0, 0, 0);
        }

        // Stage relu(y) as f16 in LDS [row][col], then coalesced 16B stores.
        #pragma unroll
        for (int t = 0; t < 4; ++t)
            #pragma unroll
            for (int i = 0; i < 4; ++i)
                ol[wv][q * 4 + i][t * 16 + l15] = (f16)fmaxf(acc2[t][i], 0.0f);

        if (r0 + srow < N) {
            const f16x8 u0 = *(const f16x8*)&ol[wv][srow][scol];
            const f16x8 u1 = *(const f16x8*)&ol[wv][srow][scol + 8];
            f16* yp = Y + (long long)(r0 + srow) * 64 + scol;
            *(f16x8*)yp = u0;
            *(f16x8*)(yp + 8) = u1;
        }
    }
}

// ---------------- lean gather: out[e][j*4..] = (f32) Y[src[e]][j*4..] -------
__global__ __launch_bounds__(256) void gather_f16_kernel(
    const f16* __restrict__ Y,      // [N][64] f16
    const int* __restrict__ src,    // [E]
    f32x4* __restrict__ out,        // [E][16] f32x4
    long long total)                // E*16
{
    const long long stride = (long long)gridDim.x * blockDim.x;
    long long g = (long long)blockIdx.x * blockDim.x + threadIdx.x;

    for (; g + 3 * stride < total; g += 4 * stride) {
        const long long g0 = g, g1 = g + stride, g2 = g + 2 * stride, g3 = g + 3 * stride;
        const int n0 = src[g0 >> 4];
        const int n1 = src[g1 >> 4];
        const int n2 = src[g2 >> 4];
        const int n3 = src[g3 >> 4];
        const f16x4 v0 = *(const f16x4*)&Y[(long long)n0 * 64 + (g0 & 15) * 4];
        const f16x4 v1 = *(const f16x4*)&Y[(long long)n1 * 64 + (g1 & 15) * 4];
        const f16x4 v2 = *(const f16x4*)&Y[(long long)n2 * 64 + (g2 & 15) * 4];
        const f16x4 v3 = *(const f16x4*)&Y[(long long)n3 * 64 + (g3 & 15) * 4];
        f32x4 o0, o1, o2, o3;
        #pragma unroll
        for (int j = 0; j < 4; ++j) {
            o0[j] = (float)v0[j]; o1[j] = (float)v1[j];
            o2[j] = (float)v2[j]; o3[j] = (float)v3[j];
        }
        __builtin_nontemporal_store(o0, &out[g0]);
        __builtin_nontemporal_store(o1, &out[g1]);
        __builtin_nontemporal_store(o2, &out[g2]);
        __builtin_nontemporal_store(o3, &out[g3]);
    }
    for (; g < total; g += stride) {
        const int n = src[g >> 4];
        const f16x4 v = *(const f16x4*)&Y[(long long)n * 64 + (g & 15) * 4];
        f32x4 o;
        #pragma unroll
        for (int j = 0; j < 4; ++j) o[j] = (float)v[j];
        __builtin_nontemporal_store(o, &out[g]);
    }
}

// ---------------- Fallback (ws too small): per-edge readlane MLP ----------------
__device__ __forceinline__ float bcast_f(float v, int l) {
    return __int_as_float(__builtin_amdgcn_readlane(__float_as_int(v), l));
}

__global__ __launch_bounds__(256, 3) void mlp_nodes_kernel(
    const float* __restrict__ features,
    const int* __restrict__ idx,
    const float* __restrict__ W1, const float* __restrict__ b1,
    const float* __restrict__ W2, const float* __restrict__ b2,
    float* __restrict__ out, int nrows)
{
    const int lane   = threadIdx.x & 63;
    const int wid    = (blockIdx.x * blockDim.x + threadIdx.x) >> 6;
    const int nwaves = (gridDim.x * blockDim.x) >> 6;

    float w1c[64], w2c[64];
    #pragma unroll
    for (int k = 0; k < 64; ++k) w1c[k] = W1[k * 64 + lane];
    #pragma unroll
    for (int k = 0; k < 64; ++k) w2c[k] = W2[k * 64 + lane];
    const float hb = b1[lane];
    const float yb = b2[lane];

    for (int row = wid; row < nrows; row += nwaves) {
        const int n = idx ? idx[row] : row;
        const float x = features[(long long)n * 64 + lane];
        float a0 = hb, a1 = 0.f, a2 = 0.f, a3 = 0.f;
        #pragma unroll
        for (int k = 0; k < 64; k += 4) {
            a0 = fmaf(bcast_f(x, k + 0), w1c[k + 0], a0);
            a1 = fmaf(bcast_f(x, k + 1), w1c[k + 1], a1);
            a2 = fmaf(bcast_f(x, k + 2), w1c[k + 2], a2);
            a3 = fmaf(bcast_f(x, k + 3), w1c[k + 3], a3);
        }
        const float h = fmaxf((a0 + a1) + (a2 + a3), 0.0f);
        float c0 = yb, c1 = 0.f, c2 = 0.f, c3 = 0.f;
        #pragma unroll
        for (int k = 0; k < 64; k += 4) {
            c0 = fmaf(bcast_f(h, k + 0), w2c[k + 0], c0);
            c1 = fmaf(bcast_f(h, k + 1), w2c[k + 1], c1);
            c2 = fmaf(bcast_f(h, k + 2), w2c[k + 2], c2);
            c3 = fmaf(bcast_f(h, k + 3), w2c[k + 3], c3);
        }
        out[(long long)row * 64 + lane] = fmaxf((c0 + c1) + (c2 + c3), 0.0f);
    }
}

extern "C" void kernel_launch(void* const* d_in, const int* in_sizes, int n_in,
                              void* d_out, int out_size, void* d_ws, size_t ws_size,
                              hipStream_t stream) {
    const float* features = (const float*)d_in[0];
    const int*   src      = (const int*)  d_in[1];
    const float* W1       = (const float*)d_in[2];
    const float* b1       = (const float*)d_in[3];
    const float* W2       = (const float*)d_in[4];
    const float* b2       = (const float*)d_in[5];
    float* out = (float*)d_out;

    const int N = in_sizes[0] / 64;
    const int E = in_sizes[1];

    const size_t need = (size_t)N * 64 * sizeof(f16);
    if (ws_size >= need) {
        f16* Y = (f16*)d_ws;
        const int ntiles = (N + 15) / 16;
        // Per-node MLP: 1024 waves, ~3 tiles/wave (amortizes weight prologue).
        mlp_f16_kernel<<<256, 256, 0, stream>>>(
            features, W1, b1, W2, b2, Y, N, ntiles);
        // Lean gather: 1M threads, ~12 f32x4 each, x4 unrolled, NT stores.
        const long long total = (long long)E * 16;
        gather_f16_kernel<<<4096, 256, 0, stream>>>(
            Y, src, (f32x4*)out, total);
    } else {
        mlp_nodes_kernel<<<3072, 256, 0, stream>>>(
            features, src, W1, b1, W2, b2, out, E);
    }
}

// Round 17
// 54.465 us; speedup vs baseline: 1.1750x; 1.1750x over previous
//
#include <hip/hip_runtime.h>

typedef float f32x4 __attribute__((ext_vector_type(4)));
typedef _Float16 f16;
typedef f16 f16x8 __attribute__((ext_vector_type(8)));

// out[e] = relu(relu(features[src[e]] @ W1 + b1) @ W2 + b2)
// BEST (R14, 54.5us): cvt f32->f16 + fused per-edge gather + 2-layer MFMA MLP,
// 2-tile software pipeline, decoupled src/row prefetch, LDS-transposed 1KB
// contiguous NT stores. Runs the ~310MB mixed stream at ~6.4 TB/s — within
// ~5% of this machine's demonstrated pure-fill BW (6.6-7.0 TB/s). R16's
// split/lean-gather control proved the fused structure is NOT store-throttled.

// ---------------- features f32 -> f16 ----------------
__global__ __launch_bounds__(256) void cvt_kernel(
    const f32x4* __restrict__ in, f16x8* __restrict__ outv, int n8)
{
    const int stride = gridDim.x * blockDim.x;
    for (int i = blockIdx.x * blockDim.x + threadIdx.x; i < n8; i += stride) {
        const f32x4 a = in[2 * i];
        const f32x4 b = in[2 * i + 1];
        f16x8 o;
        #pragma unroll
        for (int j = 0; j < 4; ++j) { o[j] = (f16)a[j]; o[4 + j] = (f16)b[j]; }
        outv[i] = o;
    }
}

// ---------------- fused gather + MFMA MLP, 2-tile pipeline, split prefetch ----
__global__ __launch_bounds__(256) void fused_mlp_kernel(
    const f16* __restrict__ feat16,  // [N][64]
    const int* __restrict__ src,     // [E]
    const float* __restrict__ W1, const float* __restrict__ b1,
    const float* __restrict__ W2, const float* __restrict__ b2,
    float* __restrict__ out, int E, int ntiles)
{
    __shared__ f16   hl[2][4][16][72];  // h staging, per parity x per wave
    __shared__ float ol[4][16][68];     // out-tile staging, per wave

    const int lane = threadIdx.x & 63;
    const int wv   = threadIdx.x >> 6;
    const int l15  = lane & 15;
    const int q    = lane >> 4;

    const int gw = blockIdx.x * 4 + wv;
    const int nw = gridDim.x * 4;

    // Weight fragments in registers for the whole kernel (64 VGPRs).
    f16x8 B1f[4][2], B2f[4][2];
    #pragma unroll
    for (int t = 0; t < 4; ++t) {
        #pragma unroll
        for (int s = 0; s < 2; ++s) {
            f16x8 r1, r2;
            #pragma unroll
            for (int j = 0; j < 8; ++j) {
                const int kk = s * 32 + q * 8 + j;
                r1[j] = (f16)W1[kk * 64 + t * 16 + l15];
                r2[j] = (f16)W2[kk * 64 + t * 16 + l15];
            }
            B1f[t][s] = r1;
            B2f[t][s] = r2;
        }
    }
    float bb1[4], bb2[4];
    #pragma unroll
    for (int t = 0; t < 4; ++t) {
        bb1[t] = b1[t * 16 + l15];
        bb2[t] = b2[t * 16 + l15];
    }

    // src index for this lane's row of a tile (clamped).
    auto LOADSRC = [&](int tile) -> int {
        int er = tile * 16 + l15;
        if (er >= E) er = E - 1;
        return src[er];
    };
    // feature-row fragments from an already-resident node index.
    auto LOADROWS = [&](int nn, f16x8& A0, f16x8& A1) {
        const f16* fp = feat16 + (long long)nn * 64;
        A0 = *(const f16x8*)(fp + q * 8);
        A1 = *(const f16x8*)(fp + 32 + q * 8);
    };

    auto COMPUTE = [&](int tile, int par, const f16x8& A0, const f16x8& A1) {
        const int e0 = tile * 16;

        // Layer 1: h = relu(x @ W1 + b1).
        f32x4 acc[4];
        #pragma unroll
        for (int t = 0; t < 4; ++t) acc[t] = (f32x4){bb1[t], bb1[t], bb1[t], bb1[t]};
        #pragma unroll
        for (int t = 0; t < 4; ++t) {
            acc[t] = __builtin_amdgcn_mfma_f32_16x16x32_f16(A0, B1f[t][0], acc[t], 0, 0, 0);
            acc[t] = __builtin_amdgcn_mfma_f32_16x16x32_f16(A1, B1f[t][1], acc[t], 0, 0, 0);
        }

        // relu + f16, stage h in per-parity wave-private LDS [row][col].
        #pragma unroll
        for (int t = 0; t < 4; ++t)
            #pragma unroll
            for (int i = 0; i < 4; ++i)
                hl[par][wv][q * 4 + i][t * 16 + l15] = (f16)fmaxf(acc[t][i], 0.0f);

        // A2: lane reads h[l15][s*32+q*8..+7] (16B ds_read_b128, same wave).
        const f16x8 A2a = *(const f16x8*)&hl[par][wv][l15][q * 8];
        const f16x8 A2b = *(const f16x8*)&hl[par][wv][l15][32 + q * 8];

        // Layer 2: y = relu(h @ W2 + b2).
        f32x4 acc2[4];
        #pragma unroll
        for (int t = 0; t < 4; ++t) acc2[t] = (f32x4){bb2[t], bb2[t], bb2[t], bb2[t]};
        #pragma unroll
        for (int t = 0; t < 4; ++t) {
            acc2[t] = __builtin_amdgcn_mfma_f32_16x16x32_f16(A2a, B2f[t][0], acc2[t], 0, 0, 0);
            acc2[t] = __builtin_amdgcn_mfma_f32_16x16x32_f16(A2b, B2f[t][1], acc2[t], 0, 0, 0);
        }

        if (e0 + 16 <= E) {
            // Stage relu(y) in LDS [row][col]; then 4 x 1KB contiguous NT stores.
            #pragma unroll
            for (int t = 0; t < 4; ++t)
                #pragma unroll
                for (int i = 0; i < 4; ++i)
                    ol[wv][q * 4 + i][t * 16 + l15] = fmaxf(acc2[t][i], 0.0f);
            #pragma unroll
            for (int j = 0; j < 4; ++j) {
                const f32x4 v = *(const f32x4*)&ol[wv][4 * j + q][l15 * 4];
                __builtin_nontemporal_store(
                    v, (f32x4*)&out[(long long)(e0 + 4 * j + q) * 64 + l15 * 4]);
            }
        } else {
            #pragma unroll
            for (int t = 0; t < 4; ++t)
                #pragma unroll
                for (int i = 0; i < 4; ++i) {
                    const int row = e0 + q * 4 + i;
                    if (row < E)
                        __builtin_nontemporal_store(
                            fmaxf(acc2[t][i], 0.0f),
                            &out[(long long)row * 64 + t * 16 + l15]);
                }
        }
    };

    const int t0 = gw;
    if (t0 >= ntiles) return;
    const int step2 = 2 * nw;
    const int clampT = ntiles - 1;

    // Prologue: src for pair 0, rows for pair 0, src for pair 1.
    int sA = LOADSRC(t0);
    int sB = LOADSRC(t0 + nw <= clampT ? t0 + nw : clampT);
    f16x8 P0a, P0b, P1a, P1b, Ca, Cb, Da, Db;
    LOADROWS(sA, P0a, P0b);
    LOADROWS(sB, P1a, P1b);
    {
        int tC = t0 + step2;     if (tC > clampT) tC = clampT;
        int tD = t0 + step2 + nw; if (tD > clampT) tD = clampT;
        sA = LOADSRC(tC);
        sB = LOADSRC(tD);
    }

    for (int t = t0; t < ntiles; t += step2) {
        const int tA = t, tB = t + nw;

        // src prefetch for pair+2 (independent of everything below).
        int tE = t + 2 * step2;      if (tE > clampT) tE = clampT;
        int tF = t + 2 * step2 + nw; if (tF > clampT) tF = clampT;
        const int nE = LOADSRC(tE);
        const int nF = LOADSRC(tF);

        // row prefetch for pair+1 from already-resident indices.
        LOADROWS(sA, Ca, Cb);
        LOADROWS(sB, Da, Db);

        COMPUTE(tA, 0, P0a, P0b);
        if (tB < ntiles) COMPUTE(tB, 1, P1a, P1b);

        sA = nE; sB = nF;
        P0a = Ca; P0b = Cb;
        P1a = Da; P1b = Db;
    }
}

// ---------------- Fallback (ws too small): per-edge readlane MLP ----------------
__device__ __forceinline__ float bcast_f(float v, int l) {
    return __int_as_float(__builtin_amdgcn_readlane(__float_as_int(v), l));
}

__global__ __launch_bounds__(256, 3) void mlp_nodes_kernel(
    const float* __restrict__ features,
    const int* __restrict__ idx,
    const float* __restrict__ W1, const float* __restrict__ b1,
    const float* __restrict__ W2, const float* __restrict__ b2,
    float* __restrict__ out, int nrows)
{
    const int lane   = threadIdx.x & 63;
    const int wid    = (blockIdx.x * blockDim.x + threadIdx.x) >> 6;
    const int nwaves = (gridDim.x * blockDim.x) >> 6;

    float w1c[64], w2c[64];
    #pragma unroll
    for (int k = 0; k < 64; ++k) w1c[k] = W1[k * 64 + lane];
    #pragma unroll
    for (int k = 0; k < 64; ++k) w2c[k] = W2[k * 64 + lane];
    const float hb = b1[lane];
    const float yb = b2[lane];

    for (int row = wid; row < nrows; row += nwaves) {
        const int n = idx ? idx[row] : row;
        const float x = features[(long long)n * 64 + lane];
        float a0 = hb, a1 = 0.f, a2 = 0.f, a3 = 0.f;
        #pragma unroll
        for (int k = 0; k < 64; k += 4) {
            a0 = fmaf(bcast_f(x, k + 0), w1c[k + 0], a0);
            a1 = fmaf(bcast_f(x, k + 1), w1c[k + 1], a1);
            a2 = fmaf(bcast_f(x, k + 2), w1c[k + 2], a2);
            a3 = fmaf(bcast_f(x, k + 3), w1c[k + 3], a3);
        }
        const float h = fmaxf((a0 + a1) + (a2 + a3), 0.0f);
        float c0 = yb, c1 = 0.f, c2 = 0.f, c3 = 0.f;
        #pragma unroll
        for (int k = 0; k < 64; k += 4) {
            c0 = fmaf(bcast_f(h, k + 0), w2c[k + 0], c0);
            c1 = fmaf(bcast_f(h, k + 1), w2c[k + 1], c1);
            c2 = fmaf(bcast_f(h, k + 2), w2c[k + 2], c2);
            c3 = fmaf(bcast_f(h, k + 3), w2c[k + 3], c3);
        }
        out[(long long)row * 64 + lane] = fmaxf((c0 + c1) + (c2 + c3), 0.0f);
    }
}

extern "C" void kernel_launch(void* const* d_in, const int* in_sizes, int n_in,
                              void* d_out, int out_size, void* d_ws, size_t ws_size,
                              hipStream_t stream) {
    const float* features = (const float*)d_in[0];
    const int*   src      = (const int*)  d_in[1];
    const float* W1       = (const float*)d_in[2];
    const float* b1       = (const float*)d_in[3];
    const float* W2       = (const float*)d_in[4];
    const float* b2       = (const float*)d_in[5];
    float* out = (float*)d_out;

    const int N = in_sizes[0] / 64;
    const int E = in_sizes[1];

    const size_t need = (size_t)N * 64 * sizeof(f16);
    if (ws_size >= need) {
        f16* feat16 = (f16*)d_ws;
        cvt_kernel<<<1024, 256, 0, stream>>>(
            (const f32x4*)features, (f16x8*)feat16, N * 8);
        const int ntiles = (E + 15) / 16;
        // 1024 blocks x 4 waves = 4096 waves, ~12 tiles/wave.
        fused_mlp_kernel<<<1024, 256, 0, stream>>>(
            feat16, src, W1, b1, W2, b2, out, E, ntiles);
    } else {
        mlp_nodes_kernel<<<3072, 256, 0, stream>>>(
            features, src, W1, b1, W2, b2, out, E);
    }
}